// Round 1
// baseline (83.538 us; speedup 1.0000x reference)
//
#include <hip/hip_runtime.h>
#include <stdint.h>

// CompetitiveNetwork: per-row Sinkhorn-like iteration, MFMA bf16 formulation.
// 16 rows per wave, 1024 waves (1/SIMD). State kept transposed (D[j,r] / D[i,r])
// so each iteration is: D1 = KT_frag x AF_B ; BF = BT*rcp(D1+1) ; pack ->
// D2 = K_frag x BF_B ; AF = AT*rcp(D2+1) ; pack.  Final: BF22 & t = MWT x AF,
// Y = sum_j BF22*t (group-reduce over lanes).
// Frag<->frag transpose via v_cvt_pk_bf16_f32 + permlane32/16_swap (T12 idiom).

typedef __attribute__((ext_vector_type(8))) short s8v;   // bf16x8 MFMA operand
typedef __attribute__((ext_vector_type(4))) float f4v;   // fp32x4 MFMA acc
typedef __attribute__((ext_vector_type(4))) unsigned u4v;

#define WS_KT   0        // uint32 offsets into ws
#define WS_K    2048
#define WS_MWT  4096
#define WS_BT   6144     // 64 floats
#define NPAIR   21       // fori_loop(20) + explicit (BF;AF); final BF fused in tail

__device__ __forceinline__ unsigned f2bf(float f) {
    unsigned x = __float_as_uint(f);
    return (x + 0x7fffu + ((x >> 16) & 1u)) >> 16;   // RTNE
}

// ---------------- precompute: build bf16 A-fragments + BT into ws ------------
// Frag layout (consistent k-convention with packB below — any HW k-relabel
// cancels since both operands use it): frag(mt,kb), lane l: m = mt*16+(l&15),
// k = kb*32 + (l>>4)*8 + 2w + {lo,hi}.  Word stored at frag*256 + lane*4 + w.
__global__ void cn_precompute(const float* __restrict__ Kraw,
                              const float* __restrict__ BTraw,
                              const float* __restrict__ Wraw,
                              unsigned* __restrict__ ws) {
    const int tid = threadIdx.x;
    if (tid < 64) {
        float v = fminf(fmaxf(expf(BTraw[tid]), 0.f), 1000.f);
        reinterpret_cast<float*>(ws)[WS_BT + tid] = v;
    }
    for (int idx = tid; idx < 3 * 2048; idx += 256) {
        const int arr  = idx >> 11;          // 0=KT,1=K,2=MWT
        const int rem  = idx & 2047;
        const int mt   = rem >> 9;
        const int kb   = (rem >> 8) & 1;
        const int lane = (rem >> 2) & 63;
        const int w    = rem & 3;
        const int m    = (mt << 4) + (lane & 15);
        const int g    = lane >> 4;
        const int k0   = kb * 32 + g * 8 + 2 * w;
        float e0, e1;
        if (arr == 0) {          // KT: A[m=j][k=i] = Kc(i=k, j=m)
            e0 = fminf(fmaxf(expf(Kraw[k0 * 64 + m]),       0.f), 1000.f);
            e1 = fminf(fmaxf(expf(Kraw[(k0 + 1) * 64 + m]), 0.f), 1000.f);
        } else if (arr == 1) {   // K: A[m=i][k=j] = Kc(m, k)
            e0 = fminf(fmaxf(expf(Kraw[m * 64 + k0]),     0.f), 1000.f);
            e1 = fminf(fmaxf(expf(Kraw[m * 64 + k0 + 1]), 0.f), 1000.f);
        } else {                 // MWT: A[m=j][k=i] = Kc(k,m)*clip(W[k*64+m])
            float a  = fminf(fmaxf(expf(Kraw[k0 * 64 + m]),       0.f), 1000.f);
            float b  = fminf(fmaxf(expf(Kraw[(k0 + 1) * 64 + m]), 0.f), 1000.f);
            float w0 = fminf(fmaxf(Wraw[k0 * 64 + m],       -10.f), 10.f);
            float w1 = fminf(fmaxf(Wraw[(k0 + 1) * 64 + m], -10.f), 10.f);
            e0 = a * w0; e1 = b * w1;
        }
        ws[idx] = f2bf(e0) | (f2bf(e1) << 16);
    }
}

// ---------------- main kernel ------------------------------------------------
__device__ __forceinline__ unsigned cvtpk(float lo, float hi) {
    unsigned r;
    asm("v_cvt_pk_bf16_f32 %0, %1, %2" : "=v"(r) : "v"(lo), "v"(hi));
    return r;
}
__device__ __forceinline__ void swap32(unsigned& a, unsigned& b) {
    asm("v_permlane32_swap_b32 %0, %1" : "+v"(a), "+v"(b));
}
__device__ __forceinline__ void swap16(unsigned& a, unsigned& b) {
    asm("v_permlane16_swap_b32 %0, %1" : "+v"(a), "+v"(b));
}

union FragU { unsigned u[4]; s8v s; u4v v; };

// Pack two f32x4 D-tiles (consecutive m-tiles along the next contraction dim)
// into one B-fragment (16 k x 16 n).  D-tile layout: lane(g,r): elem q ->
// (m = t*16 + g*4 + q, col r).  B-frag: lane(g,r): word w -> k = g*8+2w+{lo,hi}.
__device__ __forceinline__ s8v packB(f4v va, f4v vb) {
    unsigned a0 = cvtpk(va[0], va[1]), a1 = cvtpk(va[2], va[3]);
    unsigned b0 = cvtpk(vb[0], vb[1]), b1 = cvtpk(vb[2], vb[3]);
    swap32(a0, b0); swap16(a0, b0);   // a0 -> w0, b0 -> w2
    swap32(a1, b1); swap16(a1, b1);   // a1 -> w1, b1 -> w3
    FragU U; U.u[0] = a0; U.u[1] = a1; U.u[2] = b0; U.u[3] = b1;
    return U.s;
}

__global__ __launch_bounds__(64, 1)
void cn_main(const float* __restrict__ AT,
             const unsigned* __restrict__ ws,
             const float* __restrict__ braw,
             float* __restrict__ out) {
    const int l  = threadIdx.x;
    const int g  = l >> 4;
    const int r  = l & 15;
    const int rb = blockIdx.x * 16;

    // static A-fragments (all in registers; 1 wave/SIMD so VGPRs are plentiful)
    s8v ktA[4][2], kA[4][2], mwtA[4][2];
    const u4v* wsv = reinterpret_cast<const u4v*>(ws);
#pragma unroll
    for (int mt = 0; mt < 4; ++mt)
#pragma unroll
        for (int kb = 0; kb < 2; ++kb) {
            FragU U;
            U.v = wsv[(0  + mt * 2 + kb) * 64 + l]; ktA[mt][kb]  = U.s;
            U.v = wsv[(8  + mt * 2 + kb) * 64 + l]; kA[mt][kb]   = U.s;
            U.v = wsv[(16 + mt * 2 + kb) * 64 + l]; mwtA[mt][kb] = U.s;
        }

    const float* BTc = reinterpret_cast<const float*>(ws) + WS_BT;
    f4v bt[4];
#pragma unroll
    for (int jt = 0; jt < 4; ++jt)
        bt[jt] = *reinterpret_cast<const f4v*>(BTc + jt * 16 + g * 4);

    f4v at[4];
#pragma unroll
    for (int it = 0; it < 4; ++it)
        at[it] = *reinterpret_cast<const f4v*>(AT + (rb + r) * 64 + it * 16 + g * 4);

    // AF0 = AT
    s8v afB[2];
    afB[0] = packB(at[0], at[1]);
    afB[1] = packB(at[2], at[3]);

    const f4v zero = {0.f, 0.f, 0.f, 0.f};

#pragma unroll 1
    for (int t = 0; t < NPAIR; ++t) {
        // D1[j,r] = sum_i KT[j,i] * AF[i,r]
        f4v d1[4];
#pragma unroll
        for (int jt = 0; jt < 4; ++jt) {
            f4v acc = zero;
            acc = __builtin_amdgcn_mfma_f32_16x16x32_bf16(ktA[jt][0], afB[0], acc, 0, 0, 0);
            acc = __builtin_amdgcn_mfma_f32_16x16x32_bf16(ktA[jt][1], afB[1], acc, 0, 0, 0);
            d1[jt] = acc;
        }
        // BF = BT * rcp(D1 + 1)
        f4v bf[4];
#pragma unroll
        for (int jt = 0; jt < 4; ++jt)
#pragma unroll
            for (int q = 0; q < 4; ++q)
                bf[jt][q] = bt[jt][q] * __builtin_amdgcn_rcpf(d1[jt][q] + 1.f);
        s8v bfB[2];
        bfB[0] = packB(bf[0], bf[1]);
        bfB[1] = packB(bf[2], bf[3]);
        // D2[i,r] = sum_j K[i,j] * BF[j,r]
        f4v d2[4];
#pragma unroll
        for (int it = 0; it < 4; ++it) {
            f4v acc = zero;
            acc = __builtin_amdgcn_mfma_f32_16x16x32_bf16(kA[it][0], bfB[0], acc, 0, 0, 0);
            acc = __builtin_amdgcn_mfma_f32_16x16x32_bf16(kA[it][1], bfB[1], acc, 0, 0, 0);
            d2[it] = acc;
        }
        // AF = AT * rcp(D2 + 1)
        f4v af[4];
#pragma unroll
        for (int it = 0; it < 4; ++it)
#pragma unroll
            for (int q = 0; q < 4; ++q)
                af[it][q] = at[it][q] * __builtin_amdgcn_rcpf(d2[it][q] + 1.f);
        afB[0] = packB(af[0], af[1]);
        afB[1] = packB(af[2], af[3]);
    }

    // tail: final BF (22nd) and t = MWT x AF, Y = sum_j BF*t
    float y = 0.f;
#pragma unroll
    for (int jt = 0; jt < 4; ++jt) {
        f4v c1 = zero, ct = zero;
        c1 = __builtin_amdgcn_mfma_f32_16x16x32_bf16(ktA[jt][0],  afB[0], c1, 0, 0, 0);
        c1 = __builtin_amdgcn_mfma_f32_16x16x32_bf16(ktA[jt][1],  afB[1], c1, 0, 0, 0);
        ct = __builtin_amdgcn_mfma_f32_16x16x32_bf16(mwtA[jt][0], afB[0], ct, 0, 0, 0);
        ct = __builtin_amdgcn_mfma_f32_16x16x32_bf16(mwtA[jt][1], afB[1], ct, 0, 0, 0);
#pragma unroll
        for (int q = 0; q < 4; ++q)
            y += bt[jt][q] * __builtin_amdgcn_rcpf(c1[q] + 1.f) * ct[q];
    }
    // reduce over lane-groups g (same r)
    y += __shfl_xor(y, 16);
    y += __shfl_xor(y, 32);

    const float bc = fminf(fmaxf(braw[0], -10.f), 10.f);
    if (l < 16) out[rb + l] = y + bc;
}

extern "C" void kernel_launch(void* const* d_in, const int* in_sizes, int n_in,
                              void* d_out, int out_size, void* d_ws, size_t ws_size,
                              hipStream_t stream) {
    (void)in_sizes; (void)n_in; (void)out_size; (void)ws_size;
    const float* AT    = (const float*)d_in[0];
    const float* Kraw  = (const float*)d_in[1];
    const float* BTraw = (const float*)d_in[2];
    const float* Wraw  = (const float*)d_in[3];
    const float* braw  = (const float*)d_in[4];
    unsigned* ws = (unsigned*)d_ws;

    hipLaunchKernelGGL(cn_precompute, dim3(1), dim3(256), 0, stream,
                       Kraw, BTraw, Wraw, ws);
    hipLaunchKernelGGL(cn_main, dim3(16384 / 16), dim3(64), 0, stream,
                       AT, ws, braw, (float*)d_out);
}

// Round 2
// 79.996 us; speedup vs baseline: 1.0443x; 1.0443x over previous
//
#include <hip/hip_runtime.h>
#include <stdint.h>

// CompetitiveNetwork: per-row Sinkhorn-like iteration, MFMA bf16 formulation.
// Single fused kernel: each block (1 wave, 16 rows) redundantly builds the
// shared K-derived bf16 A-fragments from global (K is 16KB -> L2-resident),
// then runs 21 iteration pairs of:
//   D1 = KT x AF ; BF = BT*rcp(D1+1) ; D2 = K x BF ; AF = AT*rcp(D2+1)
// with frag<->frag transpose via v_cvt_pk_bf16_f32 + permlane32/16_swap.
// Tail: final BF and t = (K.W)^T x AF, Y = sum_j BF*t, lane-group reduce.

typedef __attribute__((ext_vector_type(8))) short s8v;   // bf16x8 MFMA operand
typedef __attribute__((ext_vector_type(4))) float f4v;   // fp32x4 MFMA acc
typedef __attribute__((ext_vector_type(4))) unsigned u4v;

#define NPAIR 21   // fori_loop(20) + explicit (BF;AF); final BF fused in tail

__device__ __forceinline__ unsigned cvtpk(float lo, float hi) {
    unsigned r;
    asm("v_cvt_pk_bf16_f32 %0, %1, %2" : "=v"(r) : "v"(lo), "v"(hi));
    return r;
}
__device__ __forceinline__ void swap32(unsigned& a, unsigned& b) {
    asm("v_permlane32_swap_b32 %0, %1" : "+v"(a), "+v"(b));
}
__device__ __forceinline__ void swap16(unsigned& a, unsigned& b) {
    asm("v_permlane16_swap_b32 %0, %1" : "+v"(a), "+v"(b));
}
__device__ __forceinline__ float clipexp(float x) {
    return fminf(__expf(x), 1000.f);   // exp >= 0 always; upper clip only
}
__device__ __forceinline__ float wclip(float x) {
    return fminf(fmaxf(x, -10.f), 10.f);
}

union FragU { unsigned u[4]; s8v s; u4v v; };

// Pack two f32x4 D-tiles (consecutive m-tiles along the next contraction dim)
// into one B-fragment (16 k x 16 n).  D-tile layout: lane(g,r): elem q ->
// (m = t*16 + g*4 + q, col r).  B-frag: lane(g,r): word w -> k = g*8+2w+{lo,hi}.
__device__ __forceinline__ s8v packB(f4v va, f4v vb) {
    unsigned a0 = cvtpk(va[0], va[1]), a1 = cvtpk(va[2], va[3]);
    unsigned b0 = cvtpk(vb[0], vb[1]), b1 = cvtpk(vb[2], vb[3]);
    swap32(a0, b0); swap16(a0, b0);   // a0 -> w0, b0 -> w2
    swap32(a1, b1); swap16(a1, b1);   // a1 -> w1, b1 -> w3
    FragU U; U.u[0] = a0; U.u[1] = a1; U.u[2] = b0; U.u[3] = b1;
    return U.s;
}

__global__ __launch_bounds__(64, 1)
void cn_main(const float* __restrict__ AT,
             const float* __restrict__ Kraw,
             const float* __restrict__ BTraw,
             const float* __restrict__ Wraw,
             const float* __restrict__ braw,
             float* __restrict__ out) {
    const int l  = threadIdx.x;
    const int g  = l >> 4;
    const int r  = l & 15;
    const int rb = blockIdx.x * 16;

    // ---- build A-fragments in registers (redundant per block; K L2-resident)
    // Frag layout (k-convention consistent with packB; any HW k-relabel
    // cancels): frag(mt,kb), lane l: m = mt*16+(l&15),
    //           word w: k = kb*32 + (l>>4)*8 + 2w + {lo,hi}.
    s8v ktA[4][2], kA[4][2], mwtA[4][2];
#pragma unroll
    for (int mt = 0; mt < 4; ++mt) {
        const int mr = mt * 16 + r;
#pragma unroll
        for (int kb = 0; kb < 2; ++kb) {
            FragU ukt, uk, umw;
#pragma unroll
            for (int w = 0; w < 4; ++w) {
                const int k0 = kb * 32 + g * 8 + 2 * w;
                // KT[m=j][k=i] = clipexp(Kraw[i,j]) ; MWT = KT * Wc[i,j]
                const float eT0 = clipexp(Kraw[k0 * 64 + mr]);
                const float eT1 = clipexp(Kraw[(k0 + 1) * 64 + mr]);
                const float w0  = wclip(Wraw[k0 * 64 + mr]);
                const float w1  = wclip(Wraw[(k0 + 1) * 64 + mr]);
                // K[m=i][k=j] = clipexp(Kraw[m, k]) (contiguous pair)
                const float eK0 = clipexp(Kraw[mr * 64 + k0]);
                const float eK1 = clipexp(Kraw[mr * 64 + k0 + 1]);
                ukt.u[w] = cvtpk(eT0, eT1);
                umw.u[w] = cvtpk(eT0 * w0, eT1 * w1);
                uk.u[w]  = cvtpk(eK0, eK1);
            }
            ktA[mt][kb]  = ukt.s;
            kA[mt][kb]   = uk.s;
            mwtA[mt][kb] = umw.s;
        }
    }

    // BT = clipexp(BTraw) at j = jt*16 + g*4 + q
    f4v bt[4];
#pragma unroll
    for (int jt = 0; jt < 4; ++jt) {
        f4v v = *reinterpret_cast<const f4v*>(BTraw + jt * 16 + g * 4);
#pragma unroll
        for (int q = 0; q < 4; ++q) bt[jt][q] = clipexp(v[q]);
    }

    f4v at[4];
#pragma unroll
    for (int it = 0; it < 4; ++it)
        at[it] = *reinterpret_cast<const f4v*>(AT + (rb + r) * 64 + it * 16 + g * 4);

    // AF0 = AT
    s8v afB[2];
    afB[0] = packB(at[0], at[1]);
    afB[1] = packB(at[2], at[3]);

    const f4v zero = {0.f, 0.f, 0.f, 0.f};

#pragma unroll 1
    for (int t = 0; t < NPAIR; ++t) {
        // D1[j,r] = sum_i KT[j,i] * AF[i,r]
        f4v d1[4];
#pragma unroll
        for (int jt = 0; jt < 4; ++jt) {
            f4v acc = zero;
            acc = __builtin_amdgcn_mfma_f32_16x16x32_bf16(ktA[jt][0], afB[0], acc, 0, 0, 0);
            acc = __builtin_amdgcn_mfma_f32_16x16x32_bf16(ktA[jt][1], afB[1], acc, 0, 0, 0);
            d1[jt] = acc;
        }
        // BF = BT * rcp(D1 + 1)
        f4v bf[4];
#pragma unroll
        for (int jt = 0; jt < 4; ++jt)
#pragma unroll
            for (int q = 0; q < 4; ++q)
                bf[jt][q] = bt[jt][q] * __builtin_amdgcn_rcpf(d1[jt][q] + 1.f);
        s8v bfB[2];
        bfB[0] = packB(bf[0], bf[1]);
        bfB[1] = packB(bf[2], bf[3]);
        // D2[i,r] = sum_j K[i,j] * BF[j,r]
        f4v d2[4];
#pragma unroll
        for (int it = 0; it < 4; ++it) {
            f4v acc = zero;
            acc = __builtin_amdgcn_mfma_f32_16x16x32_bf16(kA[it][0], bfB[0], acc, 0, 0, 0);
            acc = __builtin_amdgcn_mfma_f32_16x16x32_bf16(kA[it][1], bfB[1], acc, 0, 0, 0);
            d2[it] = acc;
        }
        // AF = AT * rcp(D2 + 1)
        f4v af[4];
#pragma unroll
        for (int it = 0; it < 4; ++it)
#pragma unroll
            for (int q = 0; q < 4; ++q)
                af[it][q] = at[it][q] * __builtin_amdgcn_rcpf(d2[it][q] + 1.f);
        afB[0] = packB(af[0], af[1]);
        afB[1] = packB(af[2], af[3]);
    }

    // tail: final BF (22nd) and t = MWT x AF, Y = sum_j BF*t
    float y = 0.f;
#pragma unroll
    for (int jt = 0; jt < 4; ++jt) {
        f4v c1 = zero, ct = zero;
        c1 = __builtin_amdgcn_mfma_f32_16x16x32_bf16(ktA[jt][0],  afB[0], c1, 0, 0, 0);
        c1 = __builtin_amdgcn_mfma_f32_16x16x32_bf16(ktA[jt][1],  afB[1], c1, 0, 0, 0);
        ct = __builtin_amdgcn_mfma_f32_16x16x32_bf16(mwtA[jt][0], afB[0], ct, 0, 0, 0);
        ct = __builtin_amdgcn_mfma_f32_16x16x32_bf16(mwtA[jt][1], afB[1], ct, 0, 0, 0);
#pragma unroll
        for (int q = 0; q < 4; ++q)
            y += bt[jt][q] * __builtin_amdgcn_rcpf(c1[q] + 1.f) * ct[q];
    }
    // reduce over lane-groups g (same r)
    y += __shfl_xor(y, 16);
    y += __shfl_xor(y, 32);

    const float bc = fminf(fmaxf(braw[0], -10.f), 10.f);
    if (l < 16) out[rb + l] = y + bc;
}

extern "C" void kernel_launch(void* const* d_in, const int* in_sizes, int n_in,
                              void* d_out, int out_size, void* d_ws, size_t ws_size,
                              hipStream_t stream) {
    (void)in_sizes; (void)n_in; (void)out_size; (void)d_ws; (void)ws_size;
    const float* AT    = (const float*)d_in[0];
    const float* Kraw  = (const float*)d_in[1];
    const float* BTraw = (const float*)d_in[2];
    const float* Wraw  = (const float*)d_in[3];
    const float* braw  = (const float*)d_in[4];

    hipLaunchKernelGGL(cn_main, dim3(16384 / 16), dim3(64), 0, stream,
                       AT, Kraw, BTraw, Wraw, braw, (float*)d_out);
}